// Round 3
// baseline (744.396 us; speedup 1.0000x reference)
//
#include <hip/hip_runtime.h>
#include <stdint.h>

#define KVOL 27
#define CIN  32
#define COUT 32
#define CHUNK 9
#define NCHUNK 3

typedef short bf16x8 __attribute__((ext_vector_type(8)));
typedef float f32x4  __attribute__((ext_vector_type(4)));
typedef int   i32x4  __attribute__((ext_vector_type(4)));

// ---------------------------------------------------------------------------
// kmap_valid layout probe (1-byte bool vs int32). flag[0]=1 -> int32 layout.
// ---------------------------------------------------------------------------
__global__ void detect_valid_layout(const uint8_t* __restrict__ valid_bytes,
                                    int* __restrict__ flag) {
    __shared__ int s_sum;
    if (threadIdx.x == 0) s_sum = 0;
    __syncthreads();
    int local = 0;
    for (int g = threadIdx.x; g < 1024; g += 256) {
        local += valid_bytes[4 * g + 1] + valid_bytes[4 * g + 2] + valid_bytes[4 * g + 3];
    }
    atomicAdd(&s_sum, local);
    __syncthreads();
    if (threadIdx.x == 0) flag[0] = (s_sum == 0) ? 1 : 0;
}

__device__ inline unsigned short f2bf(float f) {
    unsigned int u = __float_as_uint(f);
    return (unsigned short)((u + 0x7fffu + ((u >> 16) & 1u)) >> 16);
}

// X (N*32 fp32) -> Xb (N*32 bf16), 8 elements per thread, 16B stores.
// Also zero-fills row N (the "invalid gather" target row).
__global__ __launch_bounds__(256)
void convert_x(const float* __restrict__ X, short* __restrict__ Xb, int n8) {
    int i = blockIdx.x * blockDim.x + threadIdx.x;
    if (i < 4) {                       // row N = bf16x8 slots n8 .. n8+3
        bf16x8 z = {};
        *((bf16x8*)Xb + (size_t)n8 + i) = z;
    }
    if (i >= n8) return;
    const float4* p = (const float4*)X + 2 * (size_t)i;
    float4 f0 = p[0], f1 = p[1];
    bf16x8 o;
    o[0] = (short)f2bf(f0.x); o[1] = (short)f2bf(f0.y);
    o[2] = (short)f2bf(f0.z); o[3] = (short)f2bf(f0.w);
    o[4] = (short)f2bf(f1.x); o[5] = (short)f2bf(f1.y);
    o[6] = (short)f2bf(f1.z); o[7] = (short)f2bf(f1.w);
    *((bf16x8*)Xb + (size_t)i) = o;
}

// W (27,ci,co) fp32 -> Wt (27,co,ci) bf16
__global__ __launch_bounds__(256)
void convert_w(const float* __restrict__ W, short* __restrict__ Wt) {
    int i = blockIdx.x * blockDim.x + threadIdx.x; // i over 27*32*32
    if (i >= KVOL * CIN * COUT) return;
    int k  = i >> 10;
    int co = (i >> 5) & 31;
    int ci = i & 31;
    Wt[i] = (short)f2bf(W[k * 1024 + ci * 32 + co]);
}

// ---------------------------------------------------------------------------
// MFMA main, v3: 9-tap chunked LDS staging (9216 B/block -> occupancy bound
// moves from LDS to the 2048-thread cap), dwordx4 nontemporal staging loads,
// uniform zero-row gathers, 1-deep software pipeline over taps.
//
// A-frag (16x16x32): lane holds A[m=lane&15][k=(lane>>4)*8+j]  (16B gather)
// B-frag:            lane holds B[k=(lane>>4)*8+j][n=lane&15]  -> Wt[k][n][k0+j]
// C/D:               D[m=(lane>>4)*4+r][n=lane&15]
// ---------------------------------------------------------------------------
__global__ __launch_bounds__(256, 8)
void sparse_conv_mfma(const short* __restrict__ Xb,
                      const short* __restrict__ Wt,
                      const float* __restrict__ bias,
                      const int* __restrict__ idx,
                      const uint8_t* __restrict__ validb,
                      const int* __restrict__ flag,
                      float* __restrict__ out, int N) {
    const int lane = threadIdx.x & 63;
    const int wave = threadIdx.x >> 6;
    const int col  = lane & 15;
    const int quad = lane >> 4;
    const int base = blockIdx.x * 256 + wave * 64;

    // Per-wave staging region: 9 taps x 64 voxels x 4B = 2304 B; 9216 B/block.
    // Wave-local => no __syncthreads ever needed.
    __shared__ int s_idx[4][CHUNK * 64];
    int* sw = &s_idx[wave][0];

    const bool int_layout = (flag[0] != 0);
    const int* validi = (const int*)validb;
    const char* XbB = (const char*)Xb;

    // Fast staging path needs all 64 voxel rows in-bounds and 16B-aligned taps.
    const bool full = ((base + 64) <= N) && ((N & 3) == 0);

    f32x4 acc[4][2] = {};
    bf16x8 a0[4], a1[4];

    auto stage = [&](int k0) {
        if (full) {
            if (int_layout) {
#pragma unroll
                for (int i = 0; i < 3; ++i) {
                    const int s = i * 64 + lane;        // slots 0..191, use <144
                    if (s < CHUNK * 16) {
                        const int t  = s >> 4;
                        const int c4 = (s & 15) << 2;
                        const size_t off = (size_t)(k0 + t) * N + base + c4;
                        i32x4 jv = __builtin_nontemporal_load((const i32x4*)(idx + off));
                        i32x4 vv = __builtin_nontemporal_load((const i32x4*)(validi + off));
                        i32x4 m;
                        m[0] = vv[0] ? jv[0] : N;
                        m[1] = vv[1] ? jv[1] : N;
                        m[2] = vv[2] ? jv[2] : N;
                        m[3] = vv[3] ? jv[3] : N;
                        *(i32x4*)&sw[t * 64 + c4] = m;
                    }
                }
            } else {
#pragma unroll
                for (int i = 0; i < 3; ++i) {
                    const int s = i * 64 + lane;
                    if (s < CHUNK * 16) {
                        const int t  = s >> 4;
                        const int c4 = (s & 15) << 2;
                        const size_t off = (size_t)(k0 + t) * N + base + c4;
                        i32x4 jv = __builtin_nontemporal_load((const i32x4*)(idx + off));
                        unsigned vb = __builtin_nontemporal_load(
                            (const unsigned*)(validb + off));
                        i32x4 m;
                        m[0] = (vb & 0x000000ffu) ? jv[0] : N;
                        m[1] = (vb & 0x0000ff00u) ? jv[1] : N;
                        m[2] = (vb & 0x00ff0000u) ? jv[2] : N;
                        m[3] = (vb & 0xff000000u) ? jv[3] : N;
                        *(i32x4*)&sw[t * 64 + c4] = m;
                    }
                }
            }
        } else {
            const int r = base + lane;
#pragma unroll
            for (int t = 0; t < CHUNK; ++t) {
                int m = N;
                if (r < N) {
                    const size_t off = (size_t)(k0 + t) * N + r;
                    const int v = int_layout ? validi[off] : (int)validb[off];
                    const int j = idx[off];
                    m = v ? j : N;
                }
                sw[t * 64 + lane] = m;
            }
        }
    };

    auto gather = [&](bf16x8 (&a)[4], int lt) {
#pragma unroll
        for (int g = 0; g < 4; ++g) {
            const unsigned j = (unsigned)sw[lt * 64 + g * 16 + col]; // LDS broadcast
            a[g] = *(const bf16x8*)(XbB + ((size_t)((unsigned)(j << 6))) + quad * 16);
        }
    };
    auto tap = [&](bf16x8 (&a)[4], int k) {
        const bf16x8 b0 = *(const bf16x8*)(Wt + (k * 1024 + col * 32 + quad * 8));
        const bf16x8 b1 = *(const bf16x8*)(Wt + (k * 1024 + (col + 16) * 32 + quad * 8));
#pragma unroll
        for (int g = 0; g < 4; ++g) {
            acc[g][0] = __builtin_amdgcn_mfma_f32_16x16x32_bf16(a[g], b0, acc[g][0], 0, 0, 0);
            acc[g][1] = __builtin_amdgcn_mfma_f32_16x16x32_bf16(a[g], b1, acc[g][1], 0, 0, 0);
        }
    };

#pragma unroll 1
    for (int c = 0; c < NCHUNK; ++c) {
        const int k0 = c * CHUNK;
        stage(k0);
        // ---- 1-deep software pipeline over the 9 taps of this chunk ----
        gather(a0, 0);
        gather(a1, 1);
        tap(a0, k0 + 0); gather(a0, 2);
        tap(a1, k0 + 1); gather(a1, 3);
        tap(a0, k0 + 2); gather(a0, 4);
        tap(a1, k0 + 3); gather(a1, 5);
        tap(a0, k0 + 4); gather(a0, 6);
        tap(a1, k0 + 5); gather(a1, 7);
        tap(a0, k0 + 6); gather(a0, 8);
        tap(a1, k0 + 7);
        tap(a0, k0 + 8);
    }

    const float bv0 = bias[col];
    const float bv1 = bias[col + 16];
#pragma unroll
    for (int g = 0; g < 4; ++g) {
#pragma unroll
        for (int rr = 0; rr < 4; ++rr) {
            const int row = base + g * 16 + quad * 4 + rr;
            if (row < N) {
                out[(size_t)row * COUT + col]      = acc[g][0][rr] + bv0;
                out[(size_t)row * COUT + col + 16] = acc[g][1][rr] + bv1;
            }
        }
    }
}

// ---------------------------------------------------------------------------
// Fallback fp32 kernel (used only if ws_size is too small for bf16 staging).
// ---------------------------------------------------------------------------
__global__ __launch_bounds__(256)
void sparse_conv_fp32(const float* __restrict__ X,
                      const float* __restrict__ W,
                      const float* __restrict__ B,
                      const int* __restrict__ idx,
                      const uint8_t* __restrict__ validb,
                      const int* __restrict__ flag,
                      float* __restrict__ out,
                      int N) {
    const int n = blockIdx.x * blockDim.x + threadIdx.x;
    if (n >= N) return;
    const bool int_layout = (flag[0] != 0);
    const int* validi = (const int*)validb;
    float acc[COUT];
#pragma unroll
    for (int co = 0; co < COUT; ++co) acc[co] = B[co];
    for (int k = 0; k < KVOL; ++k) {
        const size_t kn = (size_t)k * (size_t)N + (size_t)n;
        const int v = int_layout ? validi[kn] : (int)validb[kn];
        if (v) {
            const int j = idx[kn];
            const float4* xp = (const float4*)(X + (size_t)j * CIN);
            float xr[CIN];
#pragma unroll
            for (int q = 0; q < 8; ++q) {
                float4 t = xp[q];
                xr[4 * q + 0] = t.x; xr[4 * q + 1] = t.y;
                xr[4 * q + 2] = t.z; xr[4 * q + 3] = t.w;
            }
            const float* __restrict__ Wk = W + k * CIN * COUT;
#pragma unroll
            for (int ci = 0; ci < CIN; ++ci) {
                const float xv = xr[ci];
#pragma unroll
                for (int co = 0; co < COUT; ++co) acc[co] += xv * Wk[ci * COUT + co];
            }
        }
    }
    float4* op = (float4*)(out + (size_t)n * COUT);
#pragma unroll
    for (int q = 0; q < 8; ++q)
        op[q] = make_float4(acc[4 * q + 0], acc[4 * q + 1], acc[4 * q + 2], acc[4 * q + 3]);
}

extern "C" void kernel_launch(void* const* d_in, const int* in_sizes, int n_in,
                              void* d_out, int out_size, void* d_ws, size_t ws_size,
                              hipStream_t stream) {
    const float*   X      = (const float*)d_in[0];   // (N, 32)
    const float*   W      = (const float*)d_in[1];   // (27, 32, 32)
    const float*   B      = (const float*)d_in[2];   // (32,)
    const int*     idx    = (const int*)d_in[3];     // (27, N)
    const uint8_t* validb = (const uint8_t*)d_in[4]; // (27, N)

    const int N = in_sizes[0] / CIN;

    const size_t xb_bytes = (size_t)(N + 1) * CIN * sizeof(short); // +1 zero row
    const size_t wt_bytes = (size_t)KVOL * CIN * COUT * sizeof(short);
    const size_t need     = xb_bytes + wt_bytes + 256;

    if (ws_size >= need) {
        short* Xb  = (short*)d_ws;
        short* Wt  = (short*)((char*)d_ws + xb_bytes);
        int*   flag = (int*)((char*)d_ws + xb_bytes + wt_bytes);

        detect_valid_layout<<<1, 256, 0, stream>>>(validb, flag);

        const int n8 = (N * CIN) / 8;
        convert_x<<<(n8 + 255) / 256, 256, 0, stream>>>(X, Xb, n8);
        convert_w<<<(KVOL * CIN * COUT + 255) / 256, 256, 0, stream>>>(W, Wt);

        const int blocks = (N + 255) / 256;
        sparse_conv_mfma<<<blocks, 256, 0, stream>>>(Xb, Wt, B, idx, validb,
                                                     flag, (float*)d_out, N);
    } else {
        int* flag = (int*)d_ws;
        detect_valid_layout<<<1, 256, 0, stream>>>(validb, flag);
        const int blocks = (N + 255) / 256;
        sparse_conv_fp32<<<blocks, 256, 0, stream>>>(X, W, B, idx, validb,
                                                     flag, (float*)d_out, N);
    }
}

// Round 4
// 601.866 us; speedup vs baseline: 1.2368x; 1.2368x over previous
//
#include <hip/hip_runtime.h>
#include <stdint.h>

#define KVOL 27
#define CIN  32
#define COUT 32
#define CHUNK 9
#define NCHUNK 3

typedef short bf16x8 __attribute__((ext_vector_type(8)));
typedef float f32x4  __attribute__((ext_vector_type(4)));
typedef int   i32x4  __attribute__((ext_vector_type(4)));

// ---------------------------------------------------------------------------
// kmap_valid layout probe (1-byte bool vs int32). flag[0]=1 -> int32 layout.
// ---------------------------------------------------------------------------
__global__ void detect_valid_layout(const uint8_t* __restrict__ valid_bytes,
                                    int* __restrict__ flag) {
    __shared__ int s_sum;
    if (threadIdx.x == 0) s_sum = 0;
    __syncthreads();
    int local = 0;
    for (int g = threadIdx.x; g < 1024; g += 256) {
        local += valid_bytes[4 * g + 1] + valid_bytes[4 * g + 2] + valid_bytes[4 * g + 3];
    }
    atomicAdd(&s_sum, local);
    __syncthreads();
    if (threadIdx.x == 0) flag[0] = (s_sum == 0) ? 1 : 0;
}

__device__ inline unsigned short f2bf(float f) {
    unsigned int u = __float_as_uint(f);
    return (unsigned short)((u + 0x7fffu + ((u >> 16) & 1u)) >> 16);
}

// X (N*32 fp32) -> Xb (N*32 bf16), 8 elements per thread, 16B stores.
// Also zero-fills row N (the "invalid gather" target row).
__global__ __launch_bounds__(256)
void convert_x(const float* __restrict__ X, short* __restrict__ Xb, int n8) {
    int i = blockIdx.x * blockDim.x + threadIdx.x;
    if (i < 4) {                       // row N = bf16x8 slots n8 .. n8+3
        bf16x8 z = {};
        *((bf16x8*)Xb + (size_t)n8 + i) = z;
    }
    if (i >= n8) return;
    const float4* p = (const float4*)X + 2 * (size_t)i;
    float4 f0 = p[0], f1 = p[1];
    bf16x8 o;
    o[0] = (short)f2bf(f0.x); o[1] = (short)f2bf(f0.y);
    o[2] = (short)f2bf(f0.z); o[3] = (short)f2bf(f0.w);
    o[4] = (short)f2bf(f1.x); o[5] = (short)f2bf(f1.y);
    o[6] = (short)f2bf(f1.z); o[7] = (short)f2bf(f1.w);
    *((bf16x8*)Xb + (size_t)i) = o;
}

// W (27,ci,co) fp32 -> Wt (27,co,ci) bf16
__global__ __launch_bounds__(256)
void convert_w(const float* __restrict__ W, short* __restrict__ Wt) {
    int i = blockIdx.x * blockDim.x + threadIdx.x; // i over 27*32*32
    if (i >= KVOL * CIN * COUT) return;
    int k  = i >> 10;
    int co = (i >> 5) & 31;
    int ci = i & 31;
    Wt[i] = (short)f2bf(W[k * 1024 + ci * 32 + co]);
}

// ---------------------------------------------------------------------------
// MFMA main, v4: chunked staging with cross-chunk LDS double-buffer.
//   - launch_bounds(256,4): 128-reg budget, NO SPILLS (v3's 256,8 spilled:
//     VGPR capped at 64 -> 512MB of scratch writes, dur 295->443us).
//   - stage(c+1) issued at the TOP of chunk c into the other wave-local LDS
//     buffer: its loads are the oldest VMEM ops, so their ds_write completes
//     with a counted vmcnt while chunk-c gathers stay in flight.
//   - uniform zero-row gathers, 2-deep tap pipeline (a0/a1).
//
// A-frag (16x16x32): lane holds A[m=lane&15][k=(lane>>4)*8+j]  (16B gather)
// B-frag:            lane holds B[k=(lane>>4)*8+j][n=lane&15]  -> Wt[k][n][k0+j]
// C/D:               D[m=(lane>>4)*4+r][n=lane&15]
// ---------------------------------------------------------------------------
__global__ __launch_bounds__(256, 4)
void sparse_conv_mfma(const short* __restrict__ Xb,
                      const short* __restrict__ Wt,
                      const float* __restrict__ bias,
                      const int* __restrict__ idx,
                      const uint8_t* __restrict__ validb,
                      const int* __restrict__ flag,
                      float* __restrict__ out, int N) {
    const int lane = threadIdx.x & 63;
    const int wave = threadIdx.x >> 6;
    const int col  = lane & 15;
    const int quad = lane >> 4;
    const int base = blockIdx.x * 256 + wave * 64;

    // Per-wave double-buffered staging: 2 x 9 taps x 64 voxels x 4B = 4608 B;
    // 18432 B/block. Wave-local => no __syncthreads ever needed.
    __shared__ int s_idx[4][2][CHUNK * 64];
    int* buf0 = &s_idx[wave][0][0];
    int* buf1 = &s_idx[wave][1][0];

    const bool int_layout = (flag[0] != 0);
    const int* validi = (const int*)validb;
    const char* XbB = (const char*)Xb;

    // Fast staging path needs all 64 voxel rows in-bounds and 16B-aligned taps.
    const bool full = ((base + 64) <= N) && ((N & 3) == 0);

    f32x4 acc[4][2] = {};
    bf16x8 a0[4], a1[4];

    auto stage = [&](int* dst, int k0) {
        if (full) {
            if (int_layout) {
#pragma unroll
                for (int i = 0; i < 3; ++i) {
                    const int s = i * 64 + lane;        // slots 0..191, use <144
                    if (s < CHUNK * 16) {
                        const int t  = s >> 4;
                        const int c4 = (s & 15) << 2;
                        const size_t off = (size_t)(k0 + t) * N + base + c4;
                        i32x4 jv = __builtin_nontemporal_load((const i32x4*)(idx + off));
                        i32x4 vv = __builtin_nontemporal_load((const i32x4*)(validi + off));
                        i32x4 m;
                        m[0] = vv[0] ? jv[0] : N;
                        m[1] = vv[1] ? jv[1] : N;
                        m[2] = vv[2] ? jv[2] : N;
                        m[3] = vv[3] ? jv[3] : N;
                        *(i32x4*)&dst[t * 64 + c4] = m;
                    }
                }
            } else {
#pragma unroll
                for (int i = 0; i < 3; ++i) {
                    const int s = i * 64 + lane;
                    if (s < CHUNK * 16) {
                        const int t  = s >> 4;
                        const int c4 = (s & 15) << 2;
                        const size_t off = (size_t)(k0 + t) * N + base + c4;
                        i32x4 jv = __builtin_nontemporal_load((const i32x4*)(idx + off));
                        unsigned vb = __builtin_nontemporal_load(
                            (const unsigned*)(validb + off));
                        i32x4 m;
                        m[0] = (vb & 0x000000ffu) ? jv[0] : N;
                        m[1] = (vb & 0x0000ff00u) ? jv[1] : N;
                        m[2] = (vb & 0x00ff0000u) ? jv[2] : N;
                        m[3] = (vb & 0xff000000u) ? jv[3] : N;
                        *(i32x4*)&dst[t * 64 + c4] = m;
                    }
                }
            }
        } else {
            const int r = base + lane;
#pragma unroll
            for (int t = 0; t < CHUNK; ++t) {
                int m = N;
                if (r < N) {
                    const size_t off = (size_t)(k0 + t) * N + r;
                    const int v = int_layout ? validi[off] : (int)validb[off];
                    const int j = idx[off];
                    m = v ? j : N;
                }
                dst[t * 64 + lane] = m;
            }
        }
    };

    auto gather = [&](bf16x8 (&a)[4], const int* sw, int lt) {
#pragma unroll
        for (int g = 0; g < 4; ++g) {
            const unsigned j = (unsigned)sw[lt * 64 + g * 16 + col]; // LDS broadcast
            a[g] = *(const bf16x8*)(XbB + ((size_t)((unsigned)(j << 6))) + quad * 16);
        }
    };
    auto tap = [&](bf16x8 (&a)[4], int k) {
        const bf16x8 b0 = *(const bf16x8*)(Wt + (k * 1024 + col * 32 + quad * 8));
        const bf16x8 b1 = *(const bf16x8*)(Wt + (k * 1024 + (col + 16) * 32 + quad * 8));
#pragma unroll
        for (int g = 0; g < 4; ++g) {
            acc[g][0] = __builtin_amdgcn_mfma_f32_16x16x32_bf16(a[g], b0, acc[g][0], 0, 0, 0);
            acc[g][1] = __builtin_amdgcn_mfma_f32_16x16x32_bf16(a[g], b1, acc[g][1], 0, 0, 0);
        }
    };

    stage(buf0, 0);
#pragma unroll 1
    for (int c = 0; c < NCHUNK; ++c) {
        const int k0 = c * CHUNK;
        const int* sw = (c & 1) ? buf1 : buf0;
        int* nxt      = (c & 1) ? buf0 : buf1;
        // Prefetch next chunk's indices first: these 6 loads are the oldest
        // outstanding VMEM ops, so their LDS writes complete under a counted
        // vmcnt while this chunk's gathers are still in flight.
        if (c + 1 < NCHUNK) stage(nxt, k0 + CHUNK);
        // ---- 2-deep tap pipeline over the 9 taps of this chunk ----
        gather(a0, sw, 0);
        gather(a1, sw, 1);
        tap(a0, k0 + 0); gather(a0, sw, 2);
        tap(a1, k0 + 1); gather(a1, sw, 3);
        tap(a0, k0 + 2); gather(a0, sw, 4);
        tap(a1, k0 + 3); gather(a1, sw, 5);
        tap(a0, k0 + 4); gather(a0, sw, 6);
        tap(a1, k0 + 5); gather(a1, sw, 7);
        tap(a0, k0 + 6); gather(a0, sw, 8);
        tap(a1, k0 + 7);
        tap(a0, k0 + 8);
    }

    const float bv0 = bias[col];
    const float bv1 = bias[col + 16];
#pragma unroll
    for (int g = 0; g < 4; ++g) {
#pragma unroll
        for (int rr = 0; rr < 4; ++rr) {
            const int row = base + g * 16 + quad * 4 + rr;
            if (row < N) {
                out[(size_t)row * COUT + col]      = acc[g][0][rr] + bv0;
                out[(size_t)row * COUT + col + 16] = acc[g][1][rr] + bv1;
            }
        }
    }
}

// ---------------------------------------------------------------------------
// Fallback fp32 kernel (used only if ws_size is too small for bf16 staging).
// ---------------------------------------------------------------------------
__global__ __launch_bounds__(256)
void sparse_conv_fp32(const float* __restrict__ X,
                      const float* __restrict__ W,
                      const float* __restrict__ B,
                      const int* __restrict__ idx,
                      const uint8_t* __restrict__ validb,
                      const int* __restrict__ flag,
                      float* __restrict__ out,
                      int N) {
    const int n = blockIdx.x * blockDim.x + threadIdx.x;
    if (n >= N) return;
    const bool int_layout = (flag[0] != 0);
    const int* validi = (const int*)validb;
    float acc[COUT];
#pragma unroll
    for (int co = 0; co < COUT; ++co) acc[co] = B[co];
    for (int k = 0; k < KVOL; ++k) {
        const size_t kn = (size_t)k * (size_t)N + (size_t)n;
        const int v = int_layout ? validi[kn] : (int)validb[kn];
        if (v) {
            const int j = idx[kn];
            const float4* xp = (const float4*)(X + (size_t)j * CIN);
            float xr[CIN];
#pragma unroll
            for (int q = 0; q < 8; ++q) {
                float4 t = xp[q];
                xr[4 * q + 0] = t.x; xr[4 * q + 1] = t.y;
                xr[4 * q + 2] = t.z; xr[4 * q + 3] = t.w;
            }
            const float* __restrict__ Wk = W + k * CIN * COUT;
#pragma unroll
            for (int ci = 0; ci < CIN; ++ci) {
                const float xv = xr[ci];
#pragma unroll
                for (int co = 0; co < COUT; ++co) acc[co] += xv * Wk[ci * COUT + co];
            }
        }
    }
    float4* op = (float4*)(out + (size_t)n * COUT);
#pragma unroll
    for (int q = 0; q < 8; ++q)
        op[q] = make_float4(acc[4 * q + 0], acc[4 * q + 1], acc[4 * q + 2], acc[4 * q + 3]);
}

extern "C" void kernel_launch(void* const* d_in, const int* in_sizes, int n_in,
                              void* d_out, int out_size, void* d_ws, size_t ws_size,
                              hipStream_t stream) {
    const float*   X      = (const float*)d_in[0];   // (N, 32)
    const float*   W      = (const float*)d_in[1];   // (27, 32, 32)
    const float*   B      = (const float*)d_in[2];   // (32,)
    const int*     idx    = (const int*)d_in[3];     // (27, N)
    const uint8_t* validb = (const uint8_t*)d_in[4]; // (27, N)

    const int N = in_sizes[0] / CIN;

    const size_t xb_bytes = (size_t)(N + 1) * CIN * sizeof(short); // +1 zero row
    const size_t wt_bytes = (size_t)KVOL * CIN * COUT * sizeof(short);
    const size_t need     = xb_bytes + wt_bytes + 256;

    if (ws_size >= need) {
        short* Xb  = (short*)d_ws;
        short* Wt  = (short*)((char*)d_ws + xb_bytes);
        int*   flag = (int*)((char*)d_ws + xb_bytes + wt_bytes);

        detect_valid_layout<<<1, 256, 0, stream>>>(validb, flag);

        const int n8 = (N * CIN) / 8;
        convert_x<<<(n8 + 255) / 256, 256, 0, stream>>>(X, Xb, n8);
        convert_w<<<(KVOL * CIN * COUT + 255) / 256, 256, 0, stream>>>(W, Wt);

        const int blocks = (N + 255) / 256;
        sparse_conv_mfma<<<blocks, 256, 0, stream>>>(Xb, Wt, B, idx, validb,
                                                     flag, (float*)d_out, N);
    } else {
        int* flag = (int*)d_ws;
        detect_valid_layout<<<1, 256, 0, stream>>>(validb, flag);
        const int blocks = (N + 255) / 256;
        sparse_conv_fp32<<<blocks, 256, 0, stream>>>(X, W, B, idx, validb,
                                                     flag, (float*)d_out, N);
    }
}

// Round 5
// 572.094 us; speedup vs baseline: 1.3012x; 1.0520x over previous
//
#include <hip/hip_runtime.h>
#include <stdint.h>

#define KVOL 27
#define CIN  32
#define COUT 32
#define CHUNK 9
#define NCHUNK 3

typedef short bf16x8 __attribute__((ext_vector_type(8)));
typedef float f32x4  __attribute__((ext_vector_type(4)));
typedef int   i32x4  __attribute__((ext_vector_type(4)));

// ---------------------------------------------------------------------------
// kmap_valid layout probe (1-byte bool vs int32). flag[0]=1 -> int32 layout.
// ---------------------------------------------------------------------------
__global__ void detect_valid_layout(const uint8_t* __restrict__ valid_bytes,
                                    int* __restrict__ flag) {
    __shared__ int s_sum;
    if (threadIdx.x == 0) s_sum = 0;
    __syncthreads();
    int local = 0;
    for (int g = threadIdx.x; g < 1024; g += 256) {
        local += valid_bytes[4 * g + 1] + valid_bytes[4 * g + 2] + valid_bytes[4 * g + 3];
    }
    atomicAdd(&s_sum, local);
    __syncthreads();
    if (threadIdx.x == 0) flag[0] = (s_sum == 0) ? 1 : 0;
}

__device__ inline unsigned short f2bf(float f) {
    unsigned int u = __float_as_uint(f);
    return (unsigned short)((u + 0x7fffu + ((u >> 16) & 1u)) >> 16);
}

// X (N*32 fp32) -> Xb (N*32 bf16), 8 elements per thread, 16B stores.
// Also zero-fills row N (the "invalid gather" target row).
__global__ __launch_bounds__(256)
void convert_x(const float* __restrict__ X, short* __restrict__ Xb, int n8) {
    int i = blockIdx.x * blockDim.x + threadIdx.x;
    if (i < 4) {                       // row N = bf16x8 slots n8 .. n8+3
        bf16x8 z = {};
        *((bf16x8*)Xb + (size_t)n8 + i) = z;
    }
    if (i >= n8) return;
    const float4* p = (const float4*)X + 2 * (size_t)i;
    float4 f0 = p[0], f1 = p[1];
    bf16x8 o;
    o[0] = (short)f2bf(f0.x); o[1] = (short)f2bf(f0.y);
    o[2] = (short)f2bf(f0.z); o[3] = (short)f2bf(f0.w);
    o[4] = (short)f2bf(f1.x); o[5] = (short)f2bf(f1.y);
    o[6] = (short)f2bf(f1.z); o[7] = (short)f2bf(f1.w);
    *((bf16x8*)Xb + (size_t)i) = o;
}

// W (27,ci,co) fp32 -> Wt (27,co,ci) bf16
__global__ __launch_bounds__(256)
void convert_w(const float* __restrict__ W, short* __restrict__ Wt) {
    int i = blockIdx.x * blockDim.x + threadIdx.x; // i over 27*32*32
    if (i >= KVOL * CIN * COUT) return;
    int k  = i >> 10;
    int co = (i >> 5) & 31;
    int ci = i & 31;
    Wt[i] = (short)f2bf(W[k * 1024 + ci * 32 + co]);
}

// ---------------------------------------------------------------------------
// MFMA main, v5: v4 structure WITHOUT the register cap.
//   Evidence (R3/R4): __launch_bounds__(256,k) => unified budget 512/k, split
//   evenly arch/acc. (256,8): 32 arch -> +512MB scratch. (256,4): 64 arch ->
//   +168MB scratch. Unconstrained (R1): 60 arch + 32 acc, ZERO spill.
//   So: no min-waves arg; occupancy settles at ~5 waves/SIMD without scratch.
//   - cross-chunk LDS double-buffer: stage(c+1) issued at the TOP of chunk c.
//   - nontemporal output stores: keep the 125MB write stream from evicting
//     the Xb gather working set (64MB) out of L3.
//
// A-frag (16x16x32): lane holds A[m=lane&15][k=(lane>>4)*8+j]  (16B gather)
// B-frag:            lane holds B[k=(lane>>4)*8+j][n=lane&15]  -> Wt[k][n][k0+j]
// C/D:               D[m=(lane>>4)*4+r][n=lane&15]
// ---------------------------------------------------------------------------
__global__ __launch_bounds__(256)
void sparse_conv_mfma(const short* __restrict__ Xb,
                      const short* __restrict__ Wt,
                      const float* __restrict__ bias,
                      const int* __restrict__ idx,
                      const uint8_t* __restrict__ validb,
                      const int* __restrict__ flag,
                      float* __restrict__ out, int N) {
    const int lane = threadIdx.x & 63;
    const int wave = threadIdx.x >> 6;
    const int col  = lane & 15;
    const int quad = lane >> 4;
    const int base = blockIdx.x * 256 + wave * 64;

    // Per-wave double-buffered staging: 2 x 9 taps x 64 voxels x 4B = 4608 B;
    // 18432 B/block. Wave-local => no __syncthreads ever needed.
    __shared__ int s_idx[4][2][CHUNK * 64];
    int* buf0 = &s_idx[wave][0][0];
    int* buf1 = &s_idx[wave][1][0];

    const bool int_layout = (flag[0] != 0);
    const int* validi = (const int*)validb;
    const char* XbB = (const char*)Xb;

    // Fast staging path needs all 64 voxel rows in-bounds and 16B-aligned taps.
    const bool full = ((base + 64) <= N) && ((N & 3) == 0);

    f32x4 acc[4][2] = {};
    bf16x8 a0[4], a1[4];

    auto stage = [&](int* dst, int k0) {
        if (full) {
            if (int_layout) {
#pragma unroll
                for (int i = 0; i < 3; ++i) {
                    const int s = i * 64 + lane;        // slots 0..191, use <144
                    if (s < CHUNK * 16) {
                        const int t  = s >> 4;
                        const int c4 = (s & 15) << 2;
                        const size_t off = (size_t)(k0 + t) * N + base + c4;
                        i32x4 jv = __builtin_nontemporal_load((const i32x4*)(idx + off));
                        i32x4 vv = __builtin_nontemporal_load((const i32x4*)(validi + off));
                        i32x4 m;
                        m[0] = vv[0] ? jv[0] : N;
                        m[1] = vv[1] ? jv[1] : N;
                        m[2] = vv[2] ? jv[2] : N;
                        m[3] = vv[3] ? jv[3] : N;
                        *(i32x4*)&dst[t * 64 + c4] = m;
                    }
                }
            } else {
#pragma unroll
                for (int i = 0; i < 3; ++i) {
                    const int s = i * 64 + lane;
                    if (s < CHUNK * 16) {
                        const int t  = s >> 4;
                        const int c4 = (s & 15) << 2;
                        const size_t off = (size_t)(k0 + t) * N + base + c4;
                        i32x4 jv = __builtin_nontemporal_load((const i32x4*)(idx + off));
                        unsigned vb = __builtin_nontemporal_load(
                            (const unsigned*)(validb + off));
                        i32x4 m;
                        m[0] = (vb & 0x000000ffu) ? jv[0] : N;
                        m[1] = (vb & 0x0000ff00u) ? jv[1] : N;
                        m[2] = (vb & 0x00ff0000u) ? jv[2] : N;
                        m[3] = (vb & 0xff000000u) ? jv[3] : N;
                        *(i32x4*)&dst[t * 64 + c4] = m;
                    }
                }
            }
        } else {
            const int r = base + lane;
#pragma unroll
            for (int t = 0; t < CHUNK; ++t) {
                int m = N;
                if (r < N) {
                    const size_t off = (size_t)(k0 + t) * N + r;
                    const int v = int_layout ? validi[off] : (int)validb[off];
                    const int j = idx[off];
                    m = v ? j : N;
                }
                dst[t * 64 + lane] = m;
            }
        }
    };

    auto gather = [&](bf16x8 (&a)[4], const int* sw, int lt) {
#pragma unroll
        for (int g = 0; g < 4; ++g) {
            const unsigned j = (unsigned)sw[lt * 64 + g * 16 + col]; // LDS broadcast
            a[g] = *(const bf16x8*)(XbB + ((size_t)((unsigned)(j << 6))) + quad * 16);
        }
    };
    auto tap = [&](bf16x8 (&a)[4], int k) {
        const bf16x8 b0 = *(const bf16x8*)(Wt + (k * 1024 + col * 32 + quad * 8));
        const bf16x8 b1 = *(const bf16x8*)(Wt + (k * 1024 + (col + 16) * 32 + quad * 8));
#pragma unroll
        for (int g = 0; g < 4; ++g) {
            acc[g][0] = __builtin_amdgcn_mfma_f32_16x16x32_bf16(a[g], b0, acc[g][0], 0, 0, 0);
            acc[g][1] = __builtin_amdgcn_mfma_f32_16x16x32_bf16(a[g], b1, acc[g][1], 0, 0, 0);
        }
    };

    stage(buf0, 0);
#pragma unroll 1
    for (int c = 0; c < NCHUNK; ++c) {
        const int k0 = c * CHUNK;
        const int* sw = (c & 1) ? buf1 : buf0;
        int* nxt      = (c & 1) ? buf0 : buf1;
        // Prefetch next chunk's indices first: these 6 loads are the oldest
        // outstanding VMEM ops, so their LDS writes complete under a counted
        // vmcnt while this chunk's gathers are still in flight.
        if (c + 1 < NCHUNK) stage(nxt, k0 + CHUNK);
        // ---- 2-deep tap pipeline over the 9 taps of this chunk ----
        gather(a0, sw, 0);
        gather(a1, sw, 1);
        tap(a0, k0 + 0); gather(a0, sw, 2);
        tap(a1, k0 + 1); gather(a1, sw, 3);
        tap(a0, k0 + 2); gather(a0, sw, 4);
        tap(a1, k0 + 3); gather(a1, sw, 5);
        tap(a0, k0 + 4); gather(a0, sw, 6);
        tap(a1, k0 + 5); gather(a1, sw, 7);
        tap(a0, k0 + 6); gather(a0, sw, 8);
        tap(a1, k0 + 7);
        tap(a0, k0 + 8);
    }

    const float bv0 = bias[col];
    const float bv1 = bias[col + 16];
#pragma unroll
    for (int g = 0; g < 4; ++g) {
#pragma unroll
        for (int rr = 0; rr < 4; ++rr) {
            const int row = base + g * 16 + quad * 4 + rr;
            if (row < N) {
                __builtin_nontemporal_store(acc[g][0][rr] + bv0,
                                            &out[(size_t)row * COUT + col]);
                __builtin_nontemporal_store(acc[g][1][rr] + bv1,
                                            &out[(size_t)row * COUT + col + 16]);
            }
        }
    }
}

// ---------------------------------------------------------------------------
// Fallback fp32 kernel (used only if ws_size is too small for bf16 staging).
// ---------------------------------------------------------------------------
__global__ __launch_bounds__(256)
void sparse_conv_fp32(const float* __restrict__ X,
                      const float* __restrict__ W,
                      const float* __restrict__ B,
                      const int* __restrict__ idx,
                      const uint8_t* __restrict__ validb,
                      const int* __restrict__ flag,
                      float* __restrict__ out,
                      int N) {
    const int n = blockIdx.x * blockDim.x + threadIdx.x;
    if (n >= N) return;
    const bool int_layout = (flag[0] != 0);
    const int* validi = (const int*)validb;
    float acc[COUT];
#pragma unroll
    for (int co = 0; co < COUT; ++co) acc[co] = B[co];
    for (int k = 0; k < KVOL; ++k) {
        const size_t kn = (size_t)k * (size_t)N + (size_t)n;
        const int v = int_layout ? validi[kn] : (int)validb[kn];
        if (v) {
            const int j = idx[kn];
            const float4* xp = (const float4*)(X + (size_t)j * CIN);
            float xr[CIN];
#pragma unroll
            for (int q = 0; q < 8; ++q) {
                float4 t = xp[q];
                xr[4 * q + 0] = t.x; xr[4 * q + 1] = t.y;
                xr[4 * q + 2] = t.z; xr[4 * q + 3] = t.w;
            }
            const float* __restrict__ Wk = W + k * CIN * COUT;
#pragma unroll
            for (int ci = 0; ci < CIN; ++ci) {
                const float xv = xr[ci];
#pragma unroll
                for (int co = 0; co < COUT; ++co) acc[co] += xv * Wk[ci * COUT + co];
            }
        }
    }
    float4* op = (float4*)(out + (size_t)n * COUT);
#pragma unroll
    for (int q = 0; q < 8; ++q)
        op[q] = make_float4(acc[4 * q + 0], acc[4 * q + 1], acc[4 * q + 2], acc[4 * q + 3]);
}

extern "C" void kernel_launch(void* const* d_in, const int* in_sizes, int n_in,
                              void* d_out, int out_size, void* d_ws, size_t ws_size,
                              hipStream_t stream) {
    const float*   X      = (const float*)d_in[0];   // (N, 32)
    const float*   W      = (const float*)d_in[1];   // (27, 32, 32)
    const float*   B      = (const float*)d_in[2];   // (32,)
    const int*     idx    = (const int*)d_in[3];     // (27, N)
    const uint8_t* validb = (const uint8_t*)d_in[4]; // (27, N)

    const int N = in_sizes[0] / CIN;

    const size_t xb_bytes = (size_t)(N + 1) * CIN * sizeof(short); // +1 zero row
    const size_t wt_bytes = (size_t)KVOL * CIN * COUT * sizeof(short);
    const size_t need     = xb_bytes + wt_bytes + 256;

    if (ws_size >= need) {
        short* Xb  = (short*)d_ws;
        short* Wt  = (short*)((char*)d_ws + xb_bytes);
        int*   flag = (int*)((char*)d_ws + xb_bytes + wt_bytes);

        detect_valid_layout<<<1, 256, 0, stream>>>(validb, flag);

        const int n8 = (N * CIN) / 8;
        convert_x<<<(n8 + 255) / 256, 256, 0, stream>>>(X, Xb, n8);
        convert_w<<<(KVOL * CIN * COUT + 255) / 256, 256, 0, stream>>>(W, Wt);

        const int blocks = (N + 255) / 256;
        sparse_conv_mfma<<<blocks, 256, 0, stream>>>(Xb, Wt, B, idx, validb,
                                                     flag, (float*)d_out, N);
    } else {
        int* flag = (int*)d_ws;
        detect_valid_layout<<<1, 256, 0, stream>>>(validb, flag);
        const int blocks = (N + 255) / 256;
        sparse_conv_fp32<<<blocks, 256, 0, stream>>>(X, W, B, idx, validb,
                                                     flag, (float*)d_out, N);
    }
}